// Round 3
// baseline (199235.095 us; speedup 1.0000x reference)
//
#include <hip/hip_runtime.h>

// ============================================================================
// KalmanNetLatentNN on MI355X (gfx950) — round 6 (= round-4 kernel; rounds 0-2
// all failed GPU acquisition; round-1 transcription introduced a paren typo in
// the GRU_Q tanhf line — fixed here; no functional changes vs round-4).
//
// vs R3 (196.6 ms), numerics-preserving changes only:
//  * two-level grid barrier: 8 leaf counters (separate cachelines, 36 blocks
//    each) + 1 root. Cuts per-line serialized device-scope RMWs 288 -> 36.
//    1024 barriers/launch make this the largest structural suspect.
//  * x_new (P6) distributed over 32 blocks (1 batch row each) instead of a
//    serial blk-0 tail that skews every P6->P7 barrier.
//  * Q-prologue computes only the block's own 16-row half (was full 32).
// ============================================================================

typedef unsigned short u16;
typedef unsigned int u32;
typedef __attribute__((ext_vector_type(8))) short short8;
typedef __attribute__((ext_vector_type(4))) float f32x4;

#define NBLK 288
#define NLEAF 8
#define LEAFSZ (NBLK / NLEAF)   // 36

__device__ __forceinline__ u16 f2bf(float f) {
  union { float f; u32 u; } v; v.f = f;
  u32 r = v.u + 0x7fffu + ((v.u >> 16) & 1u);   // RNE
  return (u16)(r >> 16);
}

// ---------------------------------------------------------------------------
// flat fp32 -> bf16 (small state vectors)
// ---------------------------------------------------------------------------
struct PJob { const float* src; u16* dst; int rows, cols; };
struct PJobs { PJob j[3]; };

__global__ void __launch_bounds__(256) pre_cvt(PJobs jobs) {
  PJob jb = jobs.j[blockIdx.y];
  int r = blockIdx.x;
  if (r >= jb.rows) return;
  const float* s = jb.src + (long)r * jb.cols;
  u16* d = jb.dst + (long)r * jb.cols;
  for (int c = threadIdx.x; c < jb.cols; c += blockDim.x) d[c] = f2bf(s[c]);
}

// ---------------------------------------------------------------------------
// fp32 -> bf16 fragment swizzle.
// frag(u, kt): 16 rows x 32 k, element (l, j): row = u*16 + (l&15),
// col = kt*32 + (l>>4)*8 + j; stored at dst + (u*NKT+kt)*512 + l*8 + j.
// ---------------------------------------------------------------------------
__global__ void __launch_bounds__(256) sw_cvt(const float* src, u16* dst,
    int cols_in, int col_off, int cols_take, int nkt, int u_row0, int u_dst0) {
  int ul = blockIdx.x;
  int u_row = u_row0 + ul;
  long dstbase = (long)(u_dst0 + ul) * nkt * 512;
  for (int i = threadIdx.x; i < nkt * 64; i += blockDim.x) {
    int kt = i >> 6, l = i & 63;
    int r = u_row * 16 + (l & 15);
    int c = kt * 32 + ((l >> 4) << 3);
    const float* s = src + (long)r * cols_in + col_off + c;
    u16 o[8];
#pragma unroll
    for (int j = 0; j < 8; ++j)
      o[j] = (c + j < cols_take) ? f2bf(s[j]) : (u16)0;
    *(ulonglong2*)(dst + dstbase + (long)kt * 512 + l * 8) = *(ulonglong2*)o;
  }
}

__global__ void __launch_bounds__(256) flat_cp(const u16* src, u16* dst, long n8) {
  long i = (long)blockIdx.x * blockDim.x + threadIdx.x;
  long stride = (long)gridDim.x * blockDim.x;
  for (; i < n8; i += stride)
    ((ulonglong2*)dst)[i] = ((const ulonglong2*)src)[i];
}

// ---------------------------------------------------------------------------
// main kernel params
// ---------------------------------------------------------------------------
struct KParams {
  const float *y_seq, *x0, *hQ0, *hSig0, *hS0, *F, *H;
  const float *biQ, *bhQ, *biSig, *bhSig, *biS, *bhS;
  const float *b1, *b2a, *b2b, *b3, *b4, *W5, *b5, *W6, *b6, *W7, *b7;
  const u16 *WiQp, *WhQp, *WiSigH, *WiSigO, *WhSigp, *WiSp, *WhSp;
  const u16 *W1p, *W2ap, *W2bp, *W3p, *W4p;
  u16 *hQbf, *hSigN, *hSigC, *hSbf, *o1, *o2a, *o2, *o3, *o6, *o7;
  float *ghSig, *ghS, *hQf, *hSigCf, *hSf, *o2f, *xprior, *dy;
  float *out;
  u32 *bar;
};

// ---------------------------------------------------------------------------
// two-level grid barrier (sense-reversing, agent scope)
// layout in bar[] (u32 index): leaf g at g*32 (128B apart), root at 256,
// generation at 288. Leaf membership: blk & 7 -> exactly 36 blocks/leaf.
// ---------------------------------------------------------------------------
__device__ __forceinline__ void gridbar(u32* bar) {
  __threadfence();
  __syncthreads();
  if (threadIdx.x == 0) {
    u32* leaf = bar + (blockIdx.x & (NLEAF - 1)) * 32;
    u32* root = bar + 256;
    u32* gen  = bar + 288;
    u32 g = __hip_atomic_load(gen, __ATOMIC_RELAXED, __HIP_MEMORY_SCOPE_AGENT);
    bool released = false;
    u32 a = __hip_atomic_fetch_add(leaf, 1u, __ATOMIC_ACQ_REL, __HIP_MEMORY_SCOPE_AGENT);
    if (a == LEAFSZ - 1) {
      // last arrival in this leaf: reset leaf (safe: next-barrier arrivals to
      // this leaf can only occur after gen bumps), promote to root.
      __hip_atomic_store(leaf, 0u, __ATOMIC_RELAXED, __HIP_MEMORY_SCOPE_AGENT);
      u32 r = __hip_atomic_fetch_add(root, 1u, __ATOMIC_ACQ_REL, __HIP_MEMORY_SCOPE_AGENT);
      if (r == NLEAF - 1) {
        __hip_atomic_store(root, 0u, __ATOMIC_RELAXED, __HIP_MEMORY_SCOPE_AGENT);
        __hip_atomic_store(gen, g + 1u, __ATOMIC_RELEASE, __HIP_MEMORY_SCOPE_AGENT);
        released = true;
      }
    }
    if (!released) {
      while (__hip_atomic_load(gen, __ATOMIC_ACQUIRE, __HIP_MEMORY_SCOPE_AGENT) == g) {
        __builtin_amdgcn_s_sleep(2);
      }
    }
  }
  __syncthreads();
  __threadfence();
}

// ---------------------------------------------------------------------------
// mm6<NCH>: NCH chunks of 6 kt; ping-pong prefetch (next chunk's 12 loads in
// flight during current chunk's MFMAs). wp: this wave's first weight frag
// (+lane*8 applied by caller); ap: act base for kt-local 0 (+lane offsets).
// ---------------------------------------------------------------------------
template<int NCH>
__device__ __forceinline__ void mm6(f32x4& acc, const u16* __restrict__ wp,
                                    const u16* __restrict__ ap) {
  short8 aw[2][6], ab[2][6];
#pragma unroll
  for (int i = 0; i < 6; ++i) {
    aw[0][i] = *(const short8*)(wp + (long)i * 512);
    ab[0][i] = *(const short8*)(ap + i * 32);
  }
#pragma unroll
  for (int ch = 0; ch < NCH; ++ch) {
    const int cur = ch & 1;
    if (ch + 1 < NCH) {
#pragma unroll
      for (int i = 0; i < 6; ++i) {
        aw[cur ^ 1][i] = *(const short8*)(wp + (long)((ch + 1) * 6 + i) * 512);
        ab[cur ^ 1][i] = *(const short8*)(ap + ((ch + 1) * 6 + i) * 32);
      }
    }
#pragma unroll
    for (int i = 0; i < 6; ++i)
      acc = __builtin_amdgcn_mfma_f32_16x16x32_bf16(aw[cur][i], ab[cur][i], acc, 0, 0, 0);
  }
}

__device__ __forceinline__ const u16* wfrag(const u16* Wf, long unit, int NKT, int kt) {
  return Wf + ((long)unit * NKT + kt) * 512;
}

// 72-kt segment: per-wave 18 kt = mm6<3>
__device__ __forceinline__ void mm72(f32x4& acc, const u16* Wf, long unit, int NKT,
                                     int wkt0, const u16* act /*hf-adjusted*/,
                                     int astride, int wave, int lane) {
  int k0 = wave * 18;
  const u16* wp = wfrag(Wf, unit, NKT, wkt0 + k0) + lane * 8;
  const u16* ap = act + (long)(lane & 15) * astride + ((lane >> 4) << 3) + k0 * 32;
  mm6<3>(acc, wp, ap);
}

// 144-kt segment: per-wave 36 kt = mm6<6>
__device__ __forceinline__ void mm144(f32x4& acc, const u16* Wf, long unit, int NKT,
                                      const u16* act, int astride, int wave, int lane) {
  int k0 = wave * 36;
  const u16* wp = wfrag(Wf, unit, NKT, k0) + lane * 8;
  const u16* ap = act + (long)(lane & 15) * astride + ((lane >> 4) << 3) + k0 * 32;
  mm6<6>(acc, wp, ap);
}

// small tail (n = 2 or 3 kt): wave w handles kt = w
__device__ __forceinline__ void mm_small(f32x4& acc, const u16* Wf, long unit, int NKT,
                                         const u16* act, int astride, int n,
                                         int wave, int lane) {
  if (wave < n) {
    const u16* wp = wfrag(Wf, unit, NKT, wave) + lane * 8;
    short8 a = *(const short8*)wp;
    short8 b = *(const short8*)(act + (long)(lane & 15) * astride + ((lane >> 4) << 3) + wave * 32);
    acc = __builtin_amdgcn_mfma_f32_16x16x32_bf16(a, b, acc, 0, 0, 0);
  }
}

// cross-wave partial-sum reduction
__device__ __forceinline__ void block_reduce(float* red, const f32x4* acc, int na,
                                             int wave, int lane, float* out) {
  for (int a = 0; a < na; ++a)
    for (int r = 0; r < 4; ++r)
      red[((wave * 4 + a) * 4 + r) * 64 + lane] = acc[a][r];
  __syncthreads();
  for (int a = 0; a < na; ++a) {
    float s = 0.f;
    for (int w = 0; w < 4; ++w) s += red[((w * 4 + a) * 4 + wave) * 64 + lane];
    out[a] = s;
  }
}

// ---------------------------------------------------------------------------
// unit kinds
// ---------------------------------------------------------------------------
// fc with one or two 72-kt act segments (NKT = 72 or 144)
__device__ __forceinline__ void fc_unit(float* red, const u16* W, int NKT, int ctl, int hfl,
    const u16* a0, int s0stride, const u16* a1, int s1stride,
    const float* bias, bool do_relu, u16* outbf, float* outf, int ostride,
    int wave, int lane) {
  f32x4 acc = {};
  mm72(acc, W, ctl, NKT, 0, a0 + (long)hfl * 16 * s0stride, s0stride, wave, lane);
  if (a1) mm72(acc, W, ctl, NKT, 72, a1 + (long)hfl * 16 * s1stride, s1stride, wave, lane);
  float v;
  block_reduce(red, &acc, 1, wave, lane, &v);
  int c = ctl * 16 + ((lane >> 4) << 2) + wave;
  int b = hfl * 16 + (lane & 15);
  v += bias[c];
  if (do_relu) v = fmaxf(v, 0.f);
  outbf[(long)b * ostride + c] = f2bf(v);
  if (outf) outf[(long)b * ostride + c] = v;
  __syncthreads();
}

// fc144 (P5: W2b, single 144-kt act)
__device__ __forceinline__ void fc144_unit(float* red, const u16* W, int ctl, int hfl,
    const u16* a0, int s0stride, const float* bias, u16* outbf, float* outf, int ostride,
    int wave, int lane) {
  f32x4 acc = {};
  mm144(acc, W, ctl, 144, a0 + (long)hfl * 16 * s0stride, s0stride, wave, lane);
  float v;
  block_reduce(red, &acc, 1, wave, lane, &v);
  int c = ctl * 16 + ((lane >> 4) << 2) + wave;
  int b = hfl * 16 + (lane & 15);
  v += bias[c];
  outbf[(long)b * ostride + c] = f2bf(v);
  if (outf) outf[(long)b * ostride + c] = v;
  __syncthreads();
}

__device__ __forceinline__ void gh_unit(float* red, const u16* Wh, const u16* actbf,
                                        const float* bh, float* ghout,
                                        int ctl, int hfl, int wave, int lane) {
  f32x4 acc[3] = {};
  const u16* ah = actbf + (long)hfl * 16 * 2304;
  for (int g = 0; g < 3; ++g)
    mm72(acc[g], Wh, g * 144 + ctl, 72, 0, ah, 2304, wave, lane);
  float v[3];
  block_reduce(red, acc, 3, wave, lane, v);
  int c = ctl * 16 + ((lane >> 4) << 2) + wave;
  int b = hfl * 16 + (lane & 15);
  for (int g = 0; g < 3; ++g)
    ghout[((long)b * 3 + g) * 2304 + c] = v[g] + bh[g * 2304 + c];
  __syncthreads();
}

// GRU gi + combine with stored gh. Main act (72 kt) + small tail.
__device__ __forceinline__ void gru_gi_unit(float* red,
    const u16* WiMain, int NKTm, const u16* a0, int s0s,
    const u16* WiTail, int NKTt, int tailUnitMul, int wkt0t,
    const u16* a1, int s1s, int ntail,
    const float* bi, const float* gh, const float* hold,
    u16* hbf, float* hf32, int ctl, int hfl, int wave, int lane) {
  f32x4 acc[3] = {};
  const u16* ah = a0 + (long)hfl * 16 * s0s;
  const u16* at = a1 + (long)hfl * 16 * s1s;
  for (int g = 0; g < 3; ++g) {
    mm72(acc[g], WiMain, g * 144 + ctl, NKTm, 0, ah, s0s, wave, lane);
    if (ntail == 0) continue;
    if (tailUnitMul) {   // tail lives in same matrix at kt offset wkt0t
      if (wave < ntail) {
        const u16* wp = wfrag(WiMain, g * 144 + ctl, NKTm, wkt0t + wave) + lane * 8;
        short8 a = *(const short8*)wp;
        short8 b = *(const short8*)(at + (long)(lane & 15) * s1s + ((lane >> 4) << 3) + wave * 32);
        acc[g] = __builtin_amdgcn_mfma_f32_16x16x32_bf16(a, b, acc[g], 0, 0, 0);
      }
    } else {             // tail is separate small matrix
      mm_small(acc[g], WiTail, g * 144 + ctl, NKTt, at, s1s, ntail, wave, lane);
    }
  }
  float v[3];
  block_reduce(red, acc, 3, wave, lane, v);
  int c = ctl * 16 + ((lane >> 4) << 2) + wave;
  int b = hfl * 16 + (lane & 15);
  float gr = gh[((long)b * 3 + 0) * 2304 + c];
  float gz = gh[((long)b * 3 + 1) * 2304 + c];
  float gn = gh[((long)b * 3 + 2) * 2304 + c];
  float r  = 1.f / (1.f + expf(-(v[0] + bi[c] + gr)));
  float z  = 1.f / (1.f + expf(-(v[1] + bi[2304 + c] + gz)));
  float nn = tanhf(v[2] + bi[4608 + c] + r * gn);
  float h  = (1.f - z) * nn + z * hold[(long)b * 2304 + c];
  hbf[(long)b * 2304 + c] = f2bf(h);
  if (hf32) hf32[(long)b * 2304 + c] = h;
  __syncthreads();
}

// ---------------------------------------------------------------------------
// the persistent kernel
// ---------------------------------------------------------------------------
__global__ void __launch_bounds__(256, 2) knet_main(KParams p) {
  const int tid  = threadIdx.x;
  const int blk  = blockIdx.x;
  const int lane = tid & 63;
  const int wave = tid >> 6;
  const int ctb  = blk >> 1;
  const int hfb  = blk & 1;

  __shared__ __align__(16) float red[4096];
  __shared__ __align__(16) float sA[1536];
  __shared__ __align__(16) float sB[1536];
  __shared__ __align__(16) float sC[1536];
  __shared__ __align__(16) u16 sO5[2048];
  __shared__ float sN1[32], sN2[32], sN3[32];

  for (int t = 0; t < 128; ++t) {
    const float* y      = p.y_seq + t * 1536;
    const float* xpost  = (t >= 1) ? (p.out + (t - 1) * 1536) : p.x0;
    const float* xpost2 = (t >= 2) ? (p.out + (t - 2) * 1536) : p.x0;
    const u16* hQbf_r = p.hQbf + (t & 1) * (32 * 2304);
    u16* hQbf_w       = p.hQbf + ((t + 1) & 1) * (32 * 2304);
    const float* hQf_r   = (t == 0) ? p.hQ0   : p.hQf;
    const float* hSigf_r = (t == 0) ? p.hSig0 : p.hSigCf;
    const float* hSf_r   = (t == 0) ? p.hS0   : p.hSf;
    float* xpr_w         = p.xprior + (t & 1) * 1536;
    const float* xprprev = p.xprior + ((t + 1) & 1) * 1536;

    // ===================== P0 =====================
    if (blk == 0) {
      if (t >= 1) {
        const float* yp = p.y_seq + (t - 1) * 1536;
        for (int i = tid; i < 1536; i += 256) sA[i] = y[i] - yp[i];
      } else {
        for (int i = tid; i < 1536; i += 256) {
          int b = i / 48, j = i - b * 48;
          float s = 0.f;
          for (int k = 0; k < 48; ++k) s += p.x0[b * 48 + k] * p.H[j * 48 + k];
          sA[i] = y[i] - s;
        }
      }
      for (int i = tid; i < 1536; i += 256) {       // x_prior = x_post @ F^T
        int b = i / 48, j = i - b * 48;
        float s = 0.f;
        for (int k = 0; k < 48; ++k) s += xpost[b * 48 + k] * p.F[j * 48 + k];
        sB[i] = s;
        xpr_w[i] = s;
      }
      __syncthreads();
      for (int i = tid; i < 1536; i += 256) {       // dy = y - x_prior @ H^T
        int b = i / 48, j = i - b * 48;
        float s = 0.f;
        for (int k = 0; k < 48; ++k) s += sB[b * 48 + k] * p.H[j * 48 + k];
        s = y[i] - s;
        sC[i] = s;
        p.dy[i] = s;
      }
      __syncthreads();
      if (tid < 32) {
        float s = 0.f;
        for (int k = 0; k < 48; ++k) { float d = sA[tid * 48 + k]; s += d * d; }
        sN1[tid] = 1.f / fmaxf(sqrtf(s), 1e-12f);
      } else if (tid < 64) {
        int b = tid - 32; float s = 0.f;
        for (int k = 0; k < 48; ++k) { float d = sC[b * 48 + k]; s += d * d; }
        sN2[b] = 1.f / fmaxf(sqrtf(s), 1e-12f);
      }
      __syncthreads();
      {
        const float* xpp = (t == 0) ? p.x0 : xprprev;
        for (int i = tid; i < 1536; i += 256) sB[i] = xpost[i] - xpp[i];
      }
      __syncthreads();
      if (tid < 32) {
        float s = 0.f;
        for (int k = 0; k < 48; ++k) { float d = sB[tid * 48 + k]; s += d * d; }
        sN3[tid] = 1.f / fmaxf(sqrtf(s), 1e-12f);
      }
      __syncthreads();
      for (int i = tid; i < 2048; i += 256) {       // o6 padded [32][64]
        int b = i >> 6, c = i & 63;
        float v = 0.f;
        if (c < 48) {
          v = p.b6[c]; float nb = sN3[b];
          for (int k = 0; k < 48; ++k) v += sB[b * 48 + k] * nb * p.W6[c * 48 + k];
          v = fmaxf(v, 0.f);
        }
        p.o6[i] = f2bf(v);
      }
      for (int i = tid; i < 3072; i += 256) {       // o7 [32][96]
        int b = i / 96, c = i - b * 96;
        float v = p.b7[c];
        float n1 = sN1[b], n2 = sN2[b];
        for (int k = 0; k < 48; ++k) v += sA[b * 48 + k] * n1 * p.W7[c * 96 + k];
        for (int k = 0; k < 48; ++k) v += sC[b * 48 + k] * n2 * p.W7[c * 96 + 48 + k];
        p.o7[i] = f2bf(fmaxf(v, 0.f));
      }
      __syncthreads();
    }

    // ---- Q prologue: fw_evol -> o5 bf16 in LDS.
    // Only this block's 16-row half (hfb) is ever consumed — compute just it.
    {
      const int rowbase = hfb * 16;
      for (int i = tid; i < 768; i += 256) {
        int r = i / 48, k = i - r * 48;
        int b = rowbase + r;
        sA[i] = xpost[b * 48 + k] - xpost2[b * 48 + k];
      }
      __syncthreads();
      if (tid < 16) {
        float s = 0.f;
        for (int k = 0; k < 48; ++k) { float d = sA[tid * 48 + k]; s += d * d; }
        sN1[tid] = 1.f / fmaxf(sqrtf(s), 1e-12f);
      }
      __syncthreads();
      for (int i = tid; i < 1024; i += 256) {       // o5 half, padded [16][64]
        int r = i >> 6, c = i & 63;
        float v = 0.f;
        if (c < 48) {
          v = p.b5[c]; float nb = sN1[r];
          for (int k = 0; k < 48; ++k) v += sA[r * 48 + k] * nb * p.W5[c * 48 + k];
          v = fmaxf(v, 0.f);
        }
        sO5[i] = f2bf(v);
      }
      __syncthreads();
    }

    // ---- GRU_Q unit
    {
      f32x4 acc[4] = {};   // r, z, n_i, n_h
      const u16* actH  = hQbf_r + (long)hfb * 16 * 2304;
      const u16* actO5 = (const u16*)sO5;           // already this block's half
      for (int g = 0; g < 2; ++g) {
        mm_small(acc[g], p.WiQp, g * 144 + ctb, 2, actO5, 64, 2, wave, lane);
        mm72(acc[g], p.WhQp, g * 144 + ctb, 72, 0, actH, 2304, wave, lane);
      }
      mm_small(acc[2], p.WiQp, 2 * 144 + ctb, 2, actO5, 64, 2, wave, lane);
      mm72(acc[3], p.WhQp, 2 * 144 + ctb, 72, 0, actH, 2304, wave, lane);
      float v[4];
      block_reduce(red, acc, 4, wave, lane, v);
      int c = ctb * 16 + ((lane >> 4) << 2) + wave;
      int b = hfb * 16 + (lane & 15);
      float r  = 1.f / (1.f + expf(-(v[0] + p.biQ[c] + p.bhQ[c])));
      float z  = 1.f / (1.f + expf(-(v[1] + p.biQ[2304 + c] + p.bhQ[2304 + c])));
      float nn = tanhf(v[2] + p.biQ[4608 + c] + r * (v[3] + p.bhQ[4608 + c]));
      float h  = (1.f - z) * nn + z * hQf_r[(long)b * 2304 + c];
      p.hQf[(long)b * 2304 + c] = h;
      hQbf_w[(long)b * 2304 + c] = f2bf(h);
      __syncthreads();
    }
    gh_unit(red, p.WhSigp, p.hSigC, p.bhSig, p.ghSig, ctb, hfb, wave, lane);
    gh_unit(red, p.WhSp,   p.hSbf,  p.bhS,   p.ghS,   ctb, hfb, wave, lane);
    gridbar(p.bar);

    // ===================== P1: GRU_Sigma =====================
    gru_gi_unit(red,
                p.WiSigH, 72, hQbf_w, 2304,
                p.WiSigO, 2, 0, 0, p.o6, 64, 2,
                p.biSig, p.ghSig, hSigf_r,
                p.hSigN, nullptr, ctb, hfb, wave, lane);
    gridbar(p.bar);

    // ===================== P2: o1 =====================
    fc_unit(red, p.W1p, 72, ctb, hfb,
            p.hSigN, 2304, nullptr, 0,
            p.b1, true, p.o1, nullptr, 2304, wave, lane);
    gridbar(p.bar);

    // ===================== P3: GRU_S =====================
    gru_gi_unit(red,
                p.WiSp, 75, p.o1, 2304,
                nullptr, 0, 1, 72, p.o7, 96, 3,
                p.biS, p.ghS, hSf_r,
                p.hSbf, p.hSf, ctb, hfb, wave, lane);
    gridbar(p.bar);

    // ===================== P4: o2a (576 units, 2/block) =====================
    for (int uu = blk; uu < 576; uu += NBLK) {
      int ctl = uu >> 1, hfl = uu & 1;
      fc_unit(red, p.W2ap, 144, ctl, hfl,
              p.hSigN, 2304, p.hSbf, 2304,
              p.b2a, true, p.o2a, nullptr, 4608, wave, lane);
    }
    gridbar(p.bar);

    // ===================== P5: o2 (KGain, no relu) =====================
    fc144_unit(red, p.W2bp, ctb, hfb,
               p.o2a, 4608, p.b2b, p.o2, p.o2f, 2304, wave, lane);
    gridbar(p.bar);

    // ===================== P6: o3 + state update =====================
    fc_unit(red, p.W3p, 144, ctb, hfb,
            p.hSbf, 2304, p.o2, 2304,
            p.b3, true, p.o3, nullptr, 2304, wave, lane);
    // x_new = x_prior + KG @ dy — distributed: block b (< 32) does batch row b
    if (blk < 32) {
      const int b = blk;
      for (int ii = tid; ii < 48; ii += 256) {
        float s = xpr_w[b * 48 + ii];
        const float* o2row = p.o2f + (long)b * 2304 + ii * 48;
        const float* dyrow = p.dy + b * 48;
        for (int j = 0; j < 48; ++j) s += o2row[j] * dyrow[j];
        p.out[t * 1536 + b * 48 + ii] = s;
      }
    }
    gridbar(p.bar);

    // ===================== P7: o4 (next hSig carry) =====================
    fc_unit(red, p.W4p, 144, ctb, hfb,
            p.hSigN, 2304, p.o3, 2304,
            p.b4, true, p.hSigC, p.hSigCf, 2304, wave, lane);
    gridbar(p.bar);
  }
}

// ---------------------------------------------------------------------------
// host launcher
// ---------------------------------------------------------------------------
extern "C" void kernel_launch(void* const* d_in, const int* in_sizes, int n_in,
                              void* d_out, int out_size, void* d_ws, size_t ws_size,
                              hipStream_t stream) {
  if (n_in < 35) return;
  if (in_sizes[0] != 128 * 32 * 48) return;
  if (in_sizes[7] != 6912 * 48) return;
  if (in_sizes[11] != 6912 * 2352) return;
  if (in_sizes[15] != 6912 * 2400) return;
  if (in_sizes[21] != 4608 * 4608) return;
  if (in_sizes[33] != 96 * 96) return;
  if (out_size != 128 * 32 * 48) return;

  float* in[35];
  for (int i = 0; i < 35; ++i) in[i] = (float*)d_in[i];

  char* base = (char*)d_ws;
  size_t used = 0;
  auto alloc = [&](size_t bytes) -> char* {
    char* r = base + used;
    used += (bytes + 255) & ~(size_t)255;
    return r;
  };
  u32* bar      = (u32*)alloc(2048);                // two-level barrier state
  u16* temp     = (u16*)alloc(2304ll * 4608 * 2);   // max half-matrix swizzle temp
  u16* WiQp     = (u16*)alloc(432ll * 2 * 512 * 2);
  u16* WiSigO   = (u16*)alloc(432ll * 2 * 512 * 2);
  u16* hQbf     = (u16*)alloc(2ll * 32 * 2304 * 2);
  u16* hSigN    = (u16*)alloc(32ll * 2304 * 2);
  u16* hSigC    = (u16*)alloc(32ll * 2304 * 2);
  u16* hSbf     = (u16*)alloc(32ll * 2304 * 2);
  u16* o1b      = (u16*)alloc(32ll * 2304 * 2);
  u16* o2ab     = (u16*)alloc(32ll * 4608 * 2);
  u16* o2b      = (u16*)alloc(32ll * 2304 * 2);
  u16* o3b      = (u16*)alloc(32ll * 2304 * 2);
  u16* o6b      = (u16*)alloc(32ll * 64 * 2);
  u16* o7b      = (u16*)alloc(32ll * 96 * 2);
  float* ghSig  = (float*)alloc(32ll * 6912 * 4);
  float* ghS    = (float*)alloc(32ll * 6912 * 4);
  float* hQf    = (float*)alloc(32ll * 2304 * 4);
  float* hSigCf = (float*)alloc(32ll * 2304 * 4);
  float* hSf    = (float*)alloc(32ll * 2304 * 4);
  float* o2f    = (float*)alloc(32ll * 2304 * 4);
  float* xprior = (float*)alloc(2ll * 1536 * 4);
  float* dy     = (float*)alloc(1536ll * 4);
  if (used > ws_size) return;

  hipMemsetAsync(bar, 0, 2048, stream);

  // ---- flat conversions of initial states
  PJobs pj;
  pj.j[0] = { in[2], hQbf,  32, 2304 };
  pj.j[1] = { in[3], hSigC, 32, 2304 };
  pj.j[2] = { in[4], hSbf,  32, 2304 };
  pre_cvt<<<dim3(32, 3), dim3(256), 0, stream>>>(pj);

  // ---- ws-direct swizzles (WiSigO must precede in[11] in-place clobber)
  sw_cvt<<<dim3(432), dim3(256), 0, stream>>>(in[7],  WiQp,   48,   0,    48, 2, 0, 0);
  sw_cvt<<<dim3(432), dim3(256), 0, stream>>>(in[11], WiSigO, 2352, 2304, 48, 2, 0, 0);

  // ---- in-place fp32->bf16 fragment swizzle for the 10 big matrices.
  // A: units [0,U/2) -> temp; B: units [U/2,U) in place (writes < n_in/4
  // bytes... strictly below the fp32 upper-half reads); C: temp -> front.
  struct IP { float* buf; int rows, ci, take, nkt; };
  const IP ips[10] = {
    { in[8],  6912, 2304, 2304, 72 },    // WhQ
    { in[11], 6912, 2352, 2304, 72 },    // WiSig head (cols [0,2304))
    { in[12], 6912, 2304, 2304, 72 },    // WhSig
    { in[15], 6912, 2400, 2400, 75 },    // WiS
    { in[16], 6912, 2304, 2304, 72 },    // WhS
    { in[19], 2304, 2304, 2304, 72 },    // W1
    { in[21], 4608, 4608, 4608, 144 },   // W2a
    { in[23], 2304, 4608, 4608, 144 },   // W2b
    { in[25], 2304, 4608, 4608, 144 },   // W3
    { in[27], 2304, 4608, 4608, 144 },   // W4
  };
  for (int m = 0; m < 10; ++m) {
    int U = ips[m].rows / 16, Uh = U / 2;
    sw_cvt<<<dim3(Uh), dim3(256), 0, stream>>>(ips[m].buf, temp,
        ips[m].ci, 0, ips[m].take, ips[m].nkt, 0, 0);
    sw_cvt<<<dim3(Uh), dim3(256), 0, stream>>>(ips[m].buf, (u16*)ips[m].buf,
        ips[m].ci, 0, ips[m].take, ips[m].nkt, Uh, Uh);
    long n8 = (long)Uh * ips[m].nkt * 64;           // (Uh*nkt*512)/8 groups
    flat_cp<<<dim3(2048), dim3(256), 0, stream>>>(temp, (u16*)ips[m].buf, n8);
  }

  KParams kp;
  kp.y_seq = in[0]; kp.x0 = in[1]; kp.hQ0 = in[2]; kp.hSig0 = in[3]; kp.hS0 = in[4];
  kp.F = in[5]; kp.H = in[6];
  kp.biQ = in[9]; kp.bhQ = in[10];
  kp.biSig = in[13]; kp.bhSig = in[14];
  kp.biS = in[17]; kp.bhS = in[18];
  kp.b1 = in[20]; kp.b2a = in[22]; kp.b2b = in[24]; kp.b3 = in[26]; kp.b4 = in[28];
  kp.W5 = in[29]; kp.b5 = in[30]; kp.W6 = in[31]; kp.b6 = in[32]; kp.W7 = in[33]; kp.b7 = in[34];
  kp.WiQp = WiQp;
  kp.WhQp = (const u16*)in[8];
  kp.WiSigH = (const u16*)in[11];
  kp.WiSigO = WiSigO;
  kp.WhSigp = (const u16*)in[12];
  kp.WiSp = (const u16*)in[15];
  kp.WhSp = (const u16*)in[16];
  kp.W1p = (const u16*)in[19];
  kp.W2ap = (const u16*)in[21];
  kp.W2bp = (const u16*)in[23];
  kp.W3p = (const u16*)in[25];
  kp.W4p = (const u16*)in[27];
  kp.hQbf = hQbf; kp.hSigN = hSigN; kp.hSigC = hSigC; kp.hSbf = hSbf;
  kp.o1 = o1b; kp.o2a = o2ab; kp.o2 = o2b; kp.o3 = o3b; kp.o6 = o6b; kp.o7 = o7b;
  kp.ghSig = ghSig; kp.ghS = ghS; kp.hQf = hQf; kp.hSigCf = hSigCf; kp.hSf = hSf;
  kp.o2f = o2f; kp.xprior = xprior; kp.dy = dy;
  kp.out = (float*)d_out;
  kp.bar = bar;

  knet_main<<<dim3(NBLK), dim3(256), 0, stream>>>(kp);
}

// Round 5
// 66475.287 us; speedup vs baseline: 2.9971x; 2.9971x over previous
//
#include <hip/hip_runtime.h>

// ============================================================================
// KalmanNetLatentNN on MI355X (gfx950) — round 8 (= round-7 fence-removal
// kernel; R7 never ran, GPU acquisition failed; re-audit found one coherence
// inconsistency, fixed here: hSigCf is a same-block carry read via plain
// cached loads, so its P7 write must be plain too (was sc1 via shared path).
// Rule: every buffer is ALL-coherent (sc1 w+r) or ALL-plain (same-block only).
//
// Theory under test (from R6 counters: 225 ms, MfmaUtil 0.23%, VALUBusy 0.20%,
// HBM 225 GB/s, GPU >99.5% idle; barrier restructure was a NULL):
// __threadfence() on gfx950 = whole-L2 writeback+invalidate; 288 blocks x 2
// fences x 1024 barriers, ~36 serialized per XCD => ~100-200 ms invariant
// cost. This kernel has ZERO fences: all cross-block data moves via relaxed
// agent-scope (sc1) accesses; ordering comes from the s_waitcnt vmcnt(0) the
// compiler emits before s_barrier plus explicit vmcnt(0) in the barrier.
// ============================================================================

typedef unsigned short u16;
typedef unsigned int u32;
typedef unsigned long long u64;
typedef __attribute__((ext_vector_type(8))) short short8;
typedef __attribute__((ext_vector_type(4))) float f32x4;

#define NBLK 288
#define NLEAF 8
#define LEAFSZ (NBLK / NLEAF)   // 36

__device__ __forceinline__ u16 f2bf(float f) {
  union { float f; u32 u; } v; v.f = f;
  u32 r = v.u + 0x7fffu + ((v.u >> 16) & 1u);   // RNE
  return (u16)(r >> 16);
}

// ---- device-coherent (agent-scope, relaxed) access helpers ----------------
__device__ __forceinline__ float gload_f(const float* p) {
  return __hip_atomic_load(p, __ATOMIC_RELAXED, __HIP_MEMORY_SCOPE_AGENT);
}
__device__ __forceinline__ void gstore_f(float* p, float v) {
  __hip_atomic_store(p, v, __ATOMIC_RELAXED, __HIP_MEMORY_SCOPE_AGENT);
}
__device__ __forceinline__ void gstore_bf(u16* p, u16 v) {
  asm volatile("global_store_short %0, %1, off sc0 sc1"
               :: "v"(p), "v"((u32)v) : "memory");
}
__device__ __forceinline__ short8 gload_frag(const u16* p) {
  u64 lo = __hip_atomic_load((const u64*)p,       __ATOMIC_RELAXED, __HIP_MEMORY_SCOPE_AGENT);
  u64 hi = __hip_atomic_load((const u64*)(p + 4), __ATOMIC_RELAXED, __HIP_MEMORY_SCOPE_AGENT);
  union { u64 q[2]; short8 v; } u; u.q[0] = lo; u.q[1] = hi; return u.v;
}

// ---------------------------------------------------------------------------
// flat fp32 -> bf16 (small state vectors)
// ---------------------------------------------------------------------------
struct PJob { const float* src; u16* dst; int rows, cols; };
struct PJobs { PJob j[3]; };

__global__ void __launch_bounds__(256) pre_cvt(PJobs jobs) {
  PJob jb = jobs.j[blockIdx.y];
  int r = blockIdx.x;
  if (r >= jb.rows) return;
  const float* s = jb.src + (long)r * jb.cols;
  u16* d = jb.dst + (long)r * jb.cols;
  for (int c = threadIdx.x; c < jb.cols; c += blockDim.x) d[c] = f2bf(s[c]);
}

// ---------------------------------------------------------------------------
// fp32 -> bf16 fragment swizzle.
// frag(u, kt): 16 rows x 32 k, element (l, j): row = u*16 + (l&15),
// col = kt*32 + (l>>4)*8 + j; stored at dst + (u*NKT+kt)*512 + l*8 + j.
// ---------------------------------------------------------------------------
__global__ void __launch_bounds__(256) sw_cvt(const float* src, u16* dst,
    int cols_in, int col_off, int cols_take, int nkt, int u_row0, int u_dst0) {
  int ul = blockIdx.x;
  int u_row = u_row0 + ul;
  long dstbase = (long)(u_dst0 + ul) * nkt * 512;
  for (int i = threadIdx.x; i < nkt * 64; i += blockDim.x) {
    int kt = i >> 6, l = i & 63;
    int r = u_row * 16 + (l & 15);
    int c = kt * 32 + ((l >> 4) << 3);
    const float* s = src + (long)r * cols_in + col_off + c;
    u16 o[8];
#pragma unroll
    for (int j = 0; j < 8; ++j)
      o[j] = (c + j < cols_take) ? f2bf(s[j]) : (u16)0;
    *(ulonglong2*)(dst + dstbase + (long)kt * 512 + l * 8) = *(ulonglong2*)o;
  }
}

__global__ void __launch_bounds__(256) flat_cp(const u16* src, u16* dst, long n8) {
  long i = (long)blockIdx.x * blockDim.x + threadIdx.x;
  long stride = (long)gridDim.x * blockDim.x;
  for (; i < n8; i += stride)
    ((ulonglong2*)dst)[i] = ((const ulonglong2*)src)[i];
}

// ---------------------------------------------------------------------------
// main kernel params
// ---------------------------------------------------------------------------
struct KParams {
  const float *y_seq, *x0, *hQ0, *hSig0, *hS0, *F, *H;
  const float *biQ, *bhQ, *biSig, *bhSig, *biS, *bhS;
  const float *b1, *b2a, *b2b, *b3, *b4, *W5, *b5, *W6, *b6, *W7, *b7;
  const u16 *WiQp, *WhQp, *WiSigH, *WiSigO, *WhSigp, *WiSp, *WhSp;
  const u16 *W1p, *W2ap, *W2bp, *W3p, *W4p;
  u16 *hQbf, *hSigN, *hSigC, *hSbf, *o1, *o2a, *o2, *o3, *o6, *o7;
  float *ghSig, *ghS, *hQf, *hSigCf, *hSf, *o2f, *xprior, *dy;
  float *out;
  u32 *bar;
};

// ---------------------------------------------------------------------------
// two-level grid barrier — ALL RELAXED agent atomics, zero cache-maintenance.
// Ordering argument:
//  * data stores are sc1 (coherence point); each wave's are completed by the
//    compiler's s_waitcnt vmcnt(0) before s_barrier (__syncthreads), so every
//    block's data is globally visible before its tid0 issues the arrive RMW.
//  * leaf/root resets are globally performed (vmcnt(0)) before the next RMW,
//    so any block observing the gen bump also observes the resets.
//  * pollers read gen at the coherence point; post-barrier agent loads issue
//    after the poll exits => observe fresh data.
// ---------------------------------------------------------------------------
__device__ __forceinline__ void gridbar(u32* bar) {
  __syncthreads();   // drains each wave's outstanding stores (vmcnt 0)
  if (threadIdx.x == 0) {
    u32* leaf = bar + (blockIdx.x & (NLEAF - 1)) * 32;
    u32* root = bar + 256;
    u32* gen  = bar + 288;
    u32 g = __hip_atomic_load(gen, __ATOMIC_RELAXED, __HIP_MEMORY_SCOPE_AGENT);
    bool released = false;
    u32 a = __hip_atomic_fetch_add(leaf, 1u, __ATOMIC_RELAXED, __HIP_MEMORY_SCOPE_AGENT);
    if (a == LEAFSZ - 1) {
      __hip_atomic_store(leaf, 0u, __ATOMIC_RELAXED, __HIP_MEMORY_SCOPE_AGENT);
      asm volatile("s_waitcnt vmcnt(0)" ::: "memory");   // reset before root RMW
      u32 r = __hip_atomic_fetch_add(root, 1u, __ATOMIC_RELAXED, __HIP_MEMORY_SCOPE_AGENT);
      if (r == NLEAF - 1) {
        __hip_atomic_store(root, 0u, __ATOMIC_RELAXED, __HIP_MEMORY_SCOPE_AGENT);
        asm volatile("s_waitcnt vmcnt(0)" ::: "memory"); // reset before gen bump
        __hip_atomic_store(gen, g + 1u, __ATOMIC_RELAXED, __HIP_MEMORY_SCOPE_AGENT);
        released = true;
      }
    }
    if (!released) {
      while (__hip_atomic_load(gen, __ATOMIC_RELAXED, __HIP_MEMORY_SCOPE_AGENT) == g) {
        __builtin_amdgcn_s_sleep(2);
      }
    }
  }
  __syncthreads();
}

// ---------------------------------------------------------------------------
// mm6<NCH, AG>: NCH chunks of 6 kt; ping-pong prefetch. Weights (wp) are
// read-only -> cached dwordx4. Acts (ap): AG=true -> agent-coherent loads
// (cross-block buffers), AG=false -> plain (LDS).
// ---------------------------------------------------------------------------
template<int NCH, bool AG>
__device__ __forceinline__ void mm6(f32x4& acc, const u16* __restrict__ wp,
                                    const u16* __restrict__ ap) {
  short8 aw[2][6], ab[2][6];
#pragma unroll
  for (int i = 0; i < 6; ++i) {
    aw[0][i] = *(const short8*)(wp + (long)i * 512);
    ab[0][i] = AG ? gload_frag(ap + i * 32) : *(const short8*)(ap + i * 32);
  }
#pragma unroll
  for (int ch = 0; ch < NCH; ++ch) {
    const int cur = ch & 1;
    if (ch + 1 < NCH) {
#pragma unroll
      for (int i = 0; i < 6; ++i) {
        aw[cur ^ 1][i] = *(const short8*)(wp + (long)((ch + 1) * 6 + i) * 512);
        ab[cur ^ 1][i] = AG ? gload_frag(ap + ((ch + 1) * 6 + i) * 32)
                            : *(const short8*)(ap + ((ch + 1) * 6 + i) * 32);
      }
    }
#pragma unroll
    for (int i = 0; i < 6; ++i)
      acc = __builtin_amdgcn_mfma_f32_16x16x32_bf16(aw[cur][i], ab[cur][i], acc, 0, 0, 0);
  }
}

__device__ __forceinline__ const u16* wfrag(const u16* Wf, long unit, int NKT, int kt) {
  return Wf + ((long)unit * NKT + kt) * 512;
}

// 72-kt segment: per-wave 18 kt = mm6<3>
template<bool AG>
__device__ __forceinline__ void mm72(f32x4& acc, const u16* Wf, long unit, int NKT,
                                     int wkt0, const u16* act /*hf-adjusted*/,
                                     int astride, int wave, int lane) {
  int k0 = wave * 18;
  const u16* wp = wfrag(Wf, unit, NKT, wkt0 + k0) + lane * 8;
  const u16* ap = act + (long)(lane & 15) * astride + ((lane >> 4) << 3) + k0 * 32;
  mm6<3, AG>(acc, wp, ap);
}

// 144-kt segment: per-wave 36 kt = mm6<6>
template<bool AG>
__device__ __forceinline__ void mm144(f32x4& acc, const u16* Wf, long unit, int NKT,
                                      const u16* act, int astride, int wave, int lane) {
  int k0 = wave * 36;
  const u16* wp = wfrag(Wf, unit, NKT, k0) + lane * 8;
  const u16* ap = act + (long)(lane & 15) * astride + ((lane >> 4) << 3) + k0 * 32;
  mm6<6, AG>(acc, wp, ap);
}

// small tail (n = 2 or 3 kt): wave w handles kt = w
template<bool AG>
__device__ __forceinline__ void mm_small(f32x4& acc, const u16* Wf, long unit, int NKT,
                                         const u16* act, int astride, int n,
                                         int wave, int lane) {
  if (wave < n) {
    const u16* wp = wfrag(Wf, unit, NKT, wave) + lane * 8;
    const u16* ap = act + (long)(lane & 15) * astride + ((lane >> 4) << 3) + wave * 32;
    short8 a = *(const short8*)wp;
    short8 b = AG ? gload_frag(ap) : *(const short8*)ap;
    acc = __builtin_amdgcn_mfma_f32_16x16x32_bf16(a, b, acc, 0, 0, 0);
  }
}

// cross-wave partial-sum reduction
__device__ __forceinline__ void block_reduce(float* red, const f32x4* acc, int na,
                                             int wave, int lane, float* out) {
  for (int a = 0; a < na; ++a)
    for (int r = 0; r < 4; ++r)
      red[((wave * 4 + a) * 4 + r) * 64 + lane] = acc[a][r];
  __syncthreads();
  for (int a = 0; a < na; ++a) {
    float s = 0.f;
    for (int w = 0; w < 4; ++w) s += red[((w * 4 + a) * 4 + wave) * 64 + lane];
    out[a] = s;
  }
}

// ---------------------------------------------------------------------------
// unit kinds
// ---------------------------------------------------------------------------
// fc with one or two 72-kt act segments (NKT = 72 or 144).
// coh_outf: o2f (cross-block) needs sc1; hSigCf (same-block carry, read via
// plain cached loads) must be written PLAIN — all-coherent-or-all-plain rule.
__device__ __forceinline__ void fc_unit(float* red, const u16* W, int NKT, int ctl, int hfl,
    const u16* a0, int s0stride, const u16* a1, int s1stride,
    const float* bias, bool do_relu, u16* outbf, float* outf, bool coh_outf,
    int ostride, int wave, int lane) {
  f32x4 acc = {};
  mm72<true>(acc, W, ctl, NKT, 0, a0 + (long)hfl * 16 * s0stride, s0stride, wave, lane);
  if (a1) mm72<true>(acc, W, ctl, NKT, 72, a1 + (long)hfl * 16 * s1stride, s1stride, wave, lane);
  float v;
  block_reduce(red, &acc, 1, wave, lane, &v);
  int c = ctl * 16 + ((lane >> 4) << 2) + wave;
  int b = hfl * 16 + (lane & 15);
  v += bias[c];
  if (do_relu) v = fmaxf(v, 0.f);
  gstore_bf(outbf + (long)b * ostride + c, f2bf(v));
  if (outf) {
    if (coh_outf) gstore_f(outf + (long)b * ostride + c, v);
    else          outf[(long)b * ostride + c] = v;
  }
  __syncthreads();
}

// fc144 (P5: W2b, single 144-kt act); o2f is cross-block -> sc1.
__device__ __forceinline__ void fc144_unit(float* red, const u16* W, int ctl, int hfl,
    const u16* a0, int s0stride, const float* bias, u16* outbf, float* outf, int ostride,
    int wave, int lane) {
  f32x4 acc = {};
  mm144<true>(acc, W, ctl, 144, a0 + (long)hfl * 16 * s0stride, s0stride, wave, lane);
  float v;
  block_reduce(red, &acc, 1, wave, lane, &v);
  int c = ctl * 16 + ((lane >> 4) << 2) + wave;
  int b = hfl * 16 + (lane & 15);
  v += bias[c];
  gstore_bf(outbf + (long)b * ostride + c, f2bf(v));
  if (outf) gstore_f(outf + (long)b * ostride + c, v);
  __syncthreads();
}

// gh output is written and later read by the SAME block -> plain cached path.
__device__ __forceinline__ void gh_unit(float* red, const u16* Wh, const u16* actbf,
                                        const float* bh, float* ghout,
                                        int ctl, int hfl, int wave, int lane) {
  f32x4 acc[3] = {};
  const u16* ah = actbf + (long)hfl * 16 * 2304;
  for (int g = 0; g < 3; ++g)
    mm72<true>(acc[g], Wh, g * 144 + ctl, 72, 0, ah, 2304, wave, lane);
  float v[3];
  block_reduce(red, acc, 3, wave, lane, v);
  int c = ctl * 16 + ((lane >> 4) << 2) + wave;
  int b = hfl * 16 + (lane & 15);
  for (int g = 0; g < 3; ++g)
    ghout[((long)b * 3 + g) * 2304 + c] = v[g] + bh[g * 2304 + c];
  __syncthreads();
}

// GRU gi + combine with stored gh. Main act (72 kt) + small tail.
__device__ __forceinline__ void gru_gi_unit(float* red,
    const u16* WiMain, int NKTm, const u16* a0, int s0s,
    const u16* WiTail, int NKTt, int tailUnitMul, int wkt0t,
    const u16* a1, int s1s, int ntail,
    const float* bi, const float* gh, const float* hold,
    u16* hbf, float* hf32, int ctl, int hfl, int wave, int lane) {
  f32x4 acc[3] = {};
  const u16* ah = a0 + (long)hfl * 16 * s0s;
  const u16* at = a1 + (long)hfl * 16 * s1s;
  for (int g = 0; g < 3; ++g) {
    mm72<true>(acc[g], WiMain, g * 144 + ctl, NKTm, 0, ah, s0s, wave, lane);
    if (ntail == 0) continue;
    if (tailUnitMul) {   // tail lives in same matrix at kt offset wkt0t
      if (wave < ntail) {
        const u16* wp = wfrag(WiMain, g * 144 + ctl, NKTm, wkt0t + wave) + lane * 8;
        short8 a = *(const short8*)wp;
        short8 b = gload_frag(at + (long)(lane & 15) * s1s + ((lane >> 4) << 3) + wave * 32);
        acc[g] = __builtin_amdgcn_mfma_f32_16x16x32_bf16(a, b, acc[g], 0, 0, 0);
      }
    } else {             // tail is separate small matrix
      mm_small<true>(acc[g], WiTail, g * 144 + ctl, NKTt, at, s1s, ntail, wave, lane);
    }
  }
  float v[3];
  block_reduce(red, acc, 3, wave, lane, v);
  int c = ctl * 16 + ((lane >> 4) << 2) + wave;
  int b = hfl * 16 + (lane & 15);
  float gr = gh[((long)b * 3 + 0) * 2304 + c];
  float gz = gh[((long)b * 3 + 1) * 2304 + c];
  float gn = gh[((long)b * 3 + 2) * 2304 + c];
  float r  = 1.f / (1.f + expf(-(v[0] + bi[c] + gr)));
  float z  = 1.f / (1.f + expf(-(v[1] + bi[2304 + c] + gz)));
  float nn = tanhf(v[2] + bi[4608 + c] + r * gn);
  float h  = (1.f - z) * nn + z * hold[(long)b * 2304 + c];
  gstore_bf(hbf + (long)b * 2304 + c, f2bf(h));
  if (hf32) hf32[(long)b * 2304 + c] = h;   // same-block carry -> plain cached
  __syncthreads();
}

// ---------------------------------------------------------------------------
// the persistent kernel
// ---------------------------------------------------------------------------
__global__ void __launch_bounds__(256, 2) knet_main(KParams p) {
  const int tid  = threadIdx.x;
  const int blk  = blockIdx.x;
  const int lane = tid & 63;
  const int wave = tid >> 6;
  const int ctb  = blk >> 1;
  const int hfb  = blk & 1;

  __shared__ __align__(16) float red[4096];
  __shared__ __align__(16) float sA[1536];
  __shared__ __align__(16) float sB[1536];
  __shared__ __align__(16) float sC[1536];
  __shared__ __align__(16) u16 sO5[2048];
  __shared__ float sN1[32], sN2[32], sN3[32];

  for (int t = 0; t < 128; ++t) {
    const float* y      = p.y_seq + t * 1536;
    const float* xpost  = (t >= 1) ? (p.out + (t - 1) * 1536) : p.x0;
    const float* xpost2 = (t >= 2) ? (p.out + (t - 2) * 1536) : p.x0;
    const u16* hQbf_r = p.hQbf + (t & 1) * (32 * 2304);
    u16* hQbf_w       = p.hQbf + ((t + 1) & 1) * (32 * 2304);
    const float* hQf_r   = (t == 0) ? p.hQ0   : p.hQf;
    const float* hSigf_r = (t == 0) ? p.hSig0 : p.hSigCf;
    const float* hSf_r   = (t == 0) ? p.hS0   : p.hSf;
    float* xpr_w         = p.xprior + (t & 1) * 1536;
    const float* xprprev = p.xprior + ((t + 1) & 1) * 1536;

    // ===================== P0 =====================
    if (blk == 0) {
      if (t >= 1) {
        const float* yp = p.y_seq + (t - 1) * 1536;
        for (int i = tid; i < 1536; i += 256) sA[i] = y[i] - yp[i];
      } else {
        for (int i = tid; i < 1536; i += 256) {
          int b = i / 48, j = i - b * 48;
          float s = 0.f;
          for (int k = 0; k < 48; ++k) s += p.x0[b * 48 + k] * p.H[j * 48 + k];
          sA[i] = y[i] - s;
        }
      }
      for (int i = tid; i < 1536; i += 256) {       // x_prior = x_post @ F^T
        int b = i / 48, j = i - b * 48;
        float s = 0.f;
        for (int k = 0; k < 48; ++k) s += gload_f(&xpost[b * 48 + k]) * p.F[j * 48 + k];
        sB[i] = s;
        gstore_f(&xpr_w[i], s);
      }
      __syncthreads();
      for (int i = tid; i < 1536; i += 256) {       // dy = y - x_prior @ H^T
        int b = i / 48, j = i - b * 48;
        float s = 0.f;
        for (int k = 0; k < 48; ++k) s += sB[b * 48 + k] * p.H[j * 48 + k];
        s = y[i] - s;
        sC[i] = s;
        gstore_f(&p.dy[i], s);
      }
      __syncthreads();
      if (tid < 32) {
        float s = 0.f;
        for (int k = 0; k < 48; ++k) { float d = sA[tid * 48 + k]; s += d * d; }
        sN1[tid] = 1.f / fmaxf(sqrtf(s), 1e-12f);
      } else if (tid < 64) {
        int b = tid - 32; float s = 0.f;
        for (int k = 0; k < 48; ++k) { float d = sC[b * 48 + k]; s += d * d; }
        sN2[b] = 1.f / fmaxf(sqrtf(s), 1e-12f);
      }
      __syncthreads();
      {
        const float* xpp = (t == 0) ? p.x0 : xprprev;
        for (int i = tid; i < 1536; i += 256)
          sB[i] = gload_f(&xpost[i]) - gload_f(&xpp[i]);
      }
      __syncthreads();
      if (tid < 32) {
        float s = 0.f;
        for (int k = 0; k < 48; ++k) { float d = sB[tid * 48 + k]; s += d * d; }
        sN3[tid] = 1.f / fmaxf(sqrtf(s), 1e-12f);
      }
      __syncthreads();
      for (int i = tid; i < 2048; i += 256) {       // o6 padded [32][64]
        int b = i >> 6, c = i & 63;
        float v = 0.f;
        if (c < 48) {
          v = p.b6[c]; float nb = sN3[b];
          for (int k = 0; k < 48; ++k) v += sB[b * 48 + k] * nb * p.W6[c * 48 + k];
          v = fmaxf(v, 0.f);
        }
        gstore_bf(&p.o6[i], f2bf(v));
      }
      for (int i = tid; i < 3072; i += 256) {       // o7 [32][96]
        int b = i / 96, c = i - b * 96;
        float v = p.b7[c];
        float n1 = sN1[b], n2 = sN2[b];
        for (int k = 0; k < 48; ++k) v += sA[b * 48 + k] * n1 * p.W7[c * 96 + k];
        for (int k = 0; k < 48; ++k) v += sC[b * 48 + k] * n2 * p.W7[c * 96 + 48 + k];
        gstore_bf(&p.o7[i], f2bf(fmaxf(v, 0.f)));
      }
      __syncthreads();
    }

    // ---- Q prologue: fw_evol -> o5 bf16 in LDS (own 16-row half only)
    {
      const int rowbase = hfb * 16;
      for (int i = tid; i < 768; i += 256) {
        int r = i / 48, k = i - r * 48;
        int b = rowbase + r;
        sA[i] = gload_f(&xpost[b * 48 + k]) - gload_f(&xpost2[b * 48 + k]);
      }
      __syncthreads();
      if (tid < 16) {
        float s = 0.f;
        for (int k = 0; k < 48; ++k) { float d = sA[tid * 48 + k]; s += d * d; }
        sN1[tid] = 1.f / fmaxf(sqrtf(s), 1e-12f);
      }
      __syncthreads();
      for (int i = tid; i < 1024; i += 256) {       // o5 half, padded [16][64]
        int r = i >> 6, c = i & 63;
        float v = 0.f;
        if (c < 48) {
          v = p.b5[c]; float nb = sN1[r];
          for (int k = 0; k < 48; ++k) v += sA[r * 48 + k] * nb * p.W5[c * 48 + k];
          v = fmaxf(v, 0.f);
        }
        sO5[i] = f2bf(v);
      }
      __syncthreads();
    }

    // ---- GRU_Q unit
    {
      f32x4 acc[4] = {};   // r, z, n_i, n_h
      const u16* actH  = hQbf_r + (long)hfb * 16 * 2304;
      const u16* actO5 = (const u16*)sO5;           // LDS, this block's half
      for (int g = 0; g < 2; ++g) {
        mm_small<false>(acc[g], p.WiQp, g * 144 + ctb, 2, actO5, 64, 2, wave, lane);
        mm72<true>(acc[g], p.WhQp, g * 144 + ctb, 72, 0, actH, 2304, wave, lane);
      }
      mm_small<false>(acc[2], p.WiQp, 2 * 144 + ctb, 2, actO5, 64, 2, wave, lane);
      mm72<true>(acc[3], p.WhQp, 2 * 144 + ctb, 72, 0, actH, 2304, wave, lane);
      float v[4];
      block_reduce(red, acc, 4, wave, lane, v);
      int c = ctb * 16 + ((lane >> 4) << 2) + wave;
      int b = hfb * 16 + (lane & 15);
      float r  = 1.f / (1.f + expf(-(v[0] + p.biQ[c] + p.bhQ[c])));
      float z  = 1.f / (1.f + expf(-(v[1] + p.biQ[2304 + c] + p.bhQ[2304 + c])));
      float nn = tanhf(v[2] + p.biQ[4608 + c] + r * (v[3] + p.bhQ[4608 + c]));
      float h  = (1.f - z) * nn + z * hQf_r[(long)b * 2304 + c];
      p.hQf[(long)b * 2304 + c] = h;                // same-block carry (plain)
      gstore_bf(hQbf_w + (long)b * 2304 + c, f2bf(h));
      __syncthreads();
    }
    gh_unit(red, p.WhSigp, p.hSigC, p.bhSig, p.ghSig, ctb, hfb, wave, lane);
    gh_unit(red, p.WhSp,   p.hSbf,  p.bhS,   p.ghS,   ctb, hfb, wave, lane);
    gridbar(p.bar);

    // ===================== P1: GRU_Sigma =====================
    gru_gi_unit(red,
                p.WiSigH, 72, hQbf_w, 2304,
                p.WiSigO, 2, 0, 0, p.o6, 64, 2,
                p.biSig, p.ghSig, hSigf_r,
                p.hSigN, nullptr, ctb, hfb, wave, lane);
    gridbar(p.bar);

    // ===================== P2: o1 =====================
    fc_unit(red, p.W1p, 72, ctb, hfb,
            p.hSigN, 2304, nullptr, 0,
            p.b1, true, p.o1, nullptr, false, 2304, wave, lane);
    gridbar(p.bar);

    // ===================== P3: GRU_S =====================
    gru_gi_unit(red,
                p.WiSp, 75, p.o1, 2304,
                nullptr, 0, 1, 72, p.o7, 96, 3,
                p.biS, p.ghS, hSf_r,
                p.hSbf, p.hSf, ctb, hfb, wave, lane);
    gridbar(p.bar);

    // ===================== P4: o2a (576 units, 2/block) =====================
    for (int uu = blk; uu < 576; uu += NBLK) {
      int ctl = uu >> 1, hfl = uu & 1;
      fc_unit(red, p.W2ap, 144, ctl, hfl,
              p.hSigN, 2304, p.hSbf, 2304,
              p.b2a, true, p.o2a, nullptr, false, 4608, wave, lane);
    }
    gridbar(p.bar);

    // ===================== P5: o2 (KGain, no relu) =====================
    fc144_unit(red, p.W2bp, ctb, hfb,
               p.o2a, 4608, p.b2b, p.o2, p.o2f, 2304, wave, lane);
    gridbar(p.bar);

    // ===================== P6: o3 + state update =====================
    fc_unit(red, p.W3p, 144, ctb, hfb,
            p.hSbf, 2304, p.o2, 2304,
            p.b3, true, p.o3, nullptr, false, 2304, wave, lane);
    // x_new = x_prior + KG @ dy — distributed: block b (< 32) does batch row b
    if (blk < 32) {
      const int b = blk;
      for (int ii = tid; ii < 48; ii += 256) {
        float s = gload_f(&xpr_w[b * 48 + ii]);
        const float* o2row = p.o2f + (long)b * 2304 + ii * 48;
        const float* dyrow = p.dy + b * 48;
        for (int j = 0; j < 48; ++j) s += gload_f(&o2row[j]) * gload_f(&dyrow[j]);
        gstore_f(&p.out[t * 1536 + b * 48 + ii], s);
      }
    }
    gridbar(p.bar);

    // ===================== P7: o4 (next hSig carry) =====================
    fc_unit(red, p.W4p, 144, ctb, hfb,
            p.hSigN, 2304, p.o3, 2304,
            p.b4, true, p.hSigC, p.hSigCf, false /*same-block carry: plain*/,
            2304, wave, lane);
    gridbar(p.bar);
  }
}

// ---------------------------------------------------------------------------
// host launcher
// ---------------------------------------------------------------------------
extern "C" void kernel_launch(void* const* d_in, const int* in_sizes, int n_in,
                              void* d_out, int out_size, void* d_ws, size_t ws_size,
                              hipStream_t stream) {
  if (n_in < 35) return;
  if (in_sizes[0] != 128 * 32 * 48) return;
  if (in_sizes[7] != 6912 * 48) return;
  if (in_sizes[11] != 6912 * 2352) return;
  if (in_sizes[15] != 6912 * 2400) return;
  if (in_sizes[21] != 4608 * 4608) return;
  if (in_sizes[33] != 96 * 96) return;
  if (out_size != 128 * 32 * 48) return;

  float* in[35];
  for (int i = 0; i < 35; ++i) in[i] = (float*)d_in[i];

  char* base = (char*)d_ws;
  size_t used = 0;
  auto alloc = [&](size_t bytes) -> char* {
    char* r = base + used;
    used += (bytes + 255) & ~(size_t)255;
    return r;
  };
  u32* bar      = (u32*)alloc(2048);                // two-level barrier state
  u16* temp     = (u16*)alloc(2304ll * 4608 * 2);   // max half-matrix swizzle temp
  u16* WiQp     = (u16*)alloc(432ll * 2 * 512 * 2);
  u16* WiSigO   = (u16*)alloc(432ll * 2 * 512 * 2);
  u16* hQbf     = (u16*)alloc(2ll * 32 * 2304 * 2);
  u16* hSigN    = (u16*)alloc(32ll * 2304 * 2);
  u16* hSigC    = (u16*)alloc(32ll * 2304 * 2);
  u16* hSbf     = (u16*)alloc(32ll * 2304 * 2);
  u16* o1b      = (u16*)alloc(32ll * 2304 * 2);
  u16* o2ab     = (u16*)alloc(32ll * 4608 * 2);
  u16* o2b      = (u16*)alloc(32ll * 2304 * 2);
  u16* o3b      = (u16*)alloc(32ll * 2304 * 2);
  u16* o6b      = (u16*)alloc(32ll * 64 * 2);
  u16* o7b      = (u16*)alloc(32ll * 96 * 2);
  float* ghSig  = (float*)alloc(32ll * 6912 * 4);
  float* ghS    = (float*)alloc(32ll * 6912 * 4);
  float* hQf    = (float*)alloc(32ll * 2304 * 4);
  float* hSigCf = (float*)alloc(32ll * 2304 * 4);
  float* hSf    = (float*)alloc(32ll * 2304 * 4);
  float* o2f    = (float*)alloc(32ll * 2304 * 4);
  float* xprior = (float*)alloc(2ll * 1536 * 4);
  float* dy     = (float*)alloc(1536ll * 4);
  if (used > ws_size) return;

  hipMemsetAsync(bar, 0, 2048, stream);

  // ---- flat conversions of initial states
  PJobs pj;
  pj.j[0] = { in[2], hQbf,  32, 2304 };
  pj.j[1] = { in[3], hSigC, 32, 2304 };
  pj.j[2] = { in[4], hSbf,  32, 2304 };
  pre_cvt<<<dim3(32, 3), dim3(256), 0, stream>>>(pj);

  // ---- ws-direct swizzles (WiSigO must precede in[11] in-place clobber)
  sw_cvt<<<dim3(432), dim3(256), 0, stream>>>(in[7],  WiQp,   48,   0,    48, 2, 0, 0);
  sw_cvt<<<dim3(432), dim3(256), 0, stream>>>(in[11], WiSigO, 2352, 2304, 48, 2, 0, 0);

  // ---- in-place fp32->bf16 fragment swizzle for the 10 big matrices.
  struct IP { float* buf; int rows, ci, take, nkt; };
  const IP ips[10] = {
    { in[8],  6912, 2304, 2304, 72 },    // WhQ
    { in[11], 6912, 2352, 2304, 72 },    // WiSig head (cols [0,2304))
    { in[12], 6912, 2304, 2304, 72 },    // WhSig
    { in[15], 6912, 2400, 2400, 75 },    // WiS
    { in[16], 6912, 2304, 2304, 72 },    // WhS
    { in[19], 2304, 2304, 2304, 72 },    // W1
    { in[21], 4608, 4608, 4608, 144 },   // W2a
    { in[23], 2304, 4608, 4608, 144 },   // W2b
    { in[25], 2304, 4608, 4608, 144 },   // W3
    { in[27], 2304, 4608, 4608, 144 },   // W4
  };
  for (int m = 0; m < 10; ++m) {
    int U = ips[m].rows / 16, Uh = U / 2;
    sw_cvt<<<dim3(Uh), dim3(256), 0, stream>>>(ips[m].buf, temp,
        ips[m].ci, 0, ips[m].take, ips[m].nkt, 0, 0);
    sw_cvt<<<dim3(Uh), dim3(256), 0, stream>>>(ips[m].buf, (u16*)ips[m].buf,
        ips[m].ci, 0, ips[m].take, ips[m].nkt, Uh, Uh);
    long n8 = (long)Uh * ips[m].nkt * 64;           // (Uh*nkt*512)/8 groups
    flat_cp<<<dim3(2048), dim3(256), 0, stream>>>(temp, (u16*)ips[m].buf, n8);
  }

  KParams kp;
  kp.y_seq = in[0]; kp.x0 = in[1]; kp.hQ0 = in[2]; kp.hSig0 = in[3]; kp.hS0 = in[4];
  kp.F = in[5]; kp.H = in[6];
  kp.biQ = in[9]; kp.bhQ = in[10];
  kp.biSig = in[13]; kp.bhSig = in[14];
  kp.biS = in[17]; kp.bhS = in[18];
  kp.b1 = in[20]; kp.b2a = in[22]; kp.b2b = in[24]; kp.b3 = in[26]; kp.b4 = in[28];
  kp.W5 = in[29]; kp.b5 = in[30]; kp.W6 = in[31]; kp.b6 = in[32]; kp.W7 = in[33]; kp.b7 = in[34];
  kp.WiQp = WiQp;
  kp.WhQp = (const u16*)in[8];
  kp.WiSigH = (const u16*)in[11];
  kp.WiSigO = WiSigO;
  kp.WhSigp = (const u16*)in[12];
  kp.WiSp = (const u16*)in[15];
  kp.WhSp = (const u16*)in[16];
  kp.W1p = (const u16*)in[19];
  kp.W2ap = (const u16*)in[21];
  kp.W2bp = (const u16*)in[23];
  kp.W3p = (const u16*)in[25];
  kp.W4p = (const u16*)in[27];
  kp.hQbf = hQbf; kp.hSigN = hSigN; kp.hSigC = hSigC; kp.hSbf = hSbf;
  kp.o1 = o1b; kp.o2a = o2ab; kp.o2 = o2b; kp.o3 = o3b; kp.o6 = o6b; kp.o7 = o7b;
  kp.ghSig = ghSig; kp.ghS = ghS; kp.hQf = hQf; kp.hSigCf = hSigCf; kp.hSf = hSf;
  kp.o2f = o2f; kp.xprior = xprior; kp.dy = dy;
  kp.out = (float*)d_out;
  kp.bar = bar;

  knet_main<<<dim3(NBLK), dim3(256), 0, stream>>>(kp);
}